// Round 3
// baseline (913.781 us; speedup 1.0000x reference)
//
#include <hip/hip_runtime.h>

#define S_LEN 2048
#define D_DIM 1024
#define H_DIM 4096
#define V_DIM 32000
#define B_SZ  4

typedef float  f32x4  __attribute__((ext_vector_type(4)));
typedef __bf16 bf16x8 __attribute__((ext_vector_type(8)));

__device__ __forceinline__ ushort f2bf(float f) {
    union { float f; unsigned u; } v; v.f = f;
    unsigned r = v.u + 0x7fffu + ((v.u >> 16) & 1u);
    return (ushort)(r >> 16);
}

// ---------------------------------------------------------------------------
// Weight transpose + fp32->bf16 convert: in fp32 [R][C] -> out bf16 [C][R]
// ---------------------------------------------------------------------------
__global__ void bt_wtranspose(const float* __restrict__ in, ushort* __restrict__ out,
                              int R, int C) {
    __shared__ ushort s[64][65];
    int r0 = blockIdx.y * 64, c0 = blockIdx.x * 64;
    int t = threadIdx.x;
    int lr = t >> 2, lc4 = (t & 3) * 16;
    const float* src = in + (size_t)(r0 + lr) * C + c0 + lc4;
#pragma unroll
    for (int j = 0; j < 4; ++j) {
        float4 v = ((const float4*)src)[j];
        s[lr][lc4 + 4 * j + 0] = f2bf(v.x);
        s[lr][lc4 + 4 * j + 1] = f2bf(v.y);
        s[lr][lc4 + 4 * j + 2] = f2bf(v.z);
        s[lr][lc4 + 4 * j + 3] = f2bf(v.w);
    }
    __syncthreads();
    int oc = t >> 2, orr = (t & 3) * 16;
    ushort tmp[16] __attribute__((aligned(16)));
#pragma unroll
    for (int j = 0; j < 16; ++j) tmp[j] = s[orr + j][oc];
    ushort* dst = out + (size_t)(c0 + oc) * R + r0 + orr;
    *(uint4*)dst        = *(uint4*)tmp;
    *(uint4*)(dst + 8)  = *(uint4*)(tmp + 8);
}

// ---------------------------------------------------------------------------
// Embedding + positional encoding
// ---------------------------------------------------------------------------
__global__ void bt_embed(const int* __restrict__ tokens, const float* __restrict__ emb,
                         const float* __restrict__ pe, float* __restrict__ h,
                         ushort* __restrict__ hbf) {
    int row = blockIdx.x;
    int s   = row & (S_LEN - 1);
    int tok = tokens[row];
    int t   = threadIdx.x;
    float4 v = ((const float4*)(emb + (size_t)tok * D_DIM))[t];
    float4 p = ((const float4*)(pe + (size_t)s * D_DIM))[t];
    v.x += p.x; v.y += p.y; v.z += p.z; v.w += p.w;
    ((float4*)(h + (size_t)row * D_DIM))[t] = v;
    uint2 pk;
    pk.x = (unsigned)f2bf(v.x) | ((unsigned)f2bf(v.y) << 16);
    pk.y = (unsigned)f2bf(v.z) | ((unsigned)f2bf(v.w) << 16);
    ((uint2*)(hbf + (size_t)row * D_DIM))[t] = pk;
}

// ---------------------------------------------------------------------------
// K-split pipelined B^T GEMM: C[m][n] = sum_k A[m][k]*B[n][k]
// BMxBN tile, BK=64 split in two K=32 halves; 512 threads (8 waves 2Mx4N);
// double-buffered LDS [khalf][row][32]; 2 phases/tile; counted vmcnt (never 0
// in main loop); raw s_barrier; setprio around MFMA cluster.
// Every phase's reads are legal for ALL waves (k-half arrival is uniform),
// unlike an M/N-half split where wave wr=1 needs rows 128+ immediately.
// ---------------------------------------------------------------------------
#define EPI_F32  0
#define EPI_BF16 1
#define EPI_RELU 2
#define EPI_RES  3

#define VMWAIT(N) asm volatile("s_waitcnt vmcnt(%0)" :: "n"(N) : "memory")
#define SBAR()  __builtin_amdgcn_s_barrier()
#define SCHED() __builtin_amdgcn_sched_barrier(0)
#define AS1 __attribute__((address_space(1)))
#define AS3 __attribute__((address_space(3)))

template <int BM, int BN, int EPI, bool CSKIP, bool KLIM>
__global__ __launch_bounds__(512, 1)
void bt_gemm8(const ushort* __restrict__ A, const ushort* __restrict__ B,
              float* Cf, ushort* Cb, const float* __restrict__ Res,
              int lda, int ldb, int ldc, int K,
              size_t strideA, size_t strideB, size_t strideC) {
    constexpr int MR = BM / 32;      // A frags per wave (wave owns BM/2 rows)
    constexpr int NR = BN / 64;      // B frags per wave (wave owns BN/4 cols)
    constexpr int Ak = BM / 128;     // stage instrs per wave per A k-half
    constexpr int Bk = BN / 128;

    __shared__ ushort lds[2][(BM + BN) * 64];

    const int bm = blockIdx.y, bn = blockIdx.x;
    if (CSKIP && bn * BN >= (bm + 1) * BM) return;

    const int tid  = threadIdx.x;
    const int lane = tid & 63;
    const int wid  = tid >> 6;
    const int wr   = wid >> 2, wc = wid & 3;
    const int r15  = lane & 15, r4 = lane >> 4;
    const int lr   = lane >> 2;          // stage: row-within-16
    const int lsl  = lane & 3;           // stage: 16B slot
    const int kswz = (r4 ^ ((r15 >> 1) & 3)) * 8;  // read-side slot XOR (ushorts)

    const ushort* Ab = A + strideA * blockIdx.z + (size_t)bm * BM * lda;
    const ushort* Bb = B + strideB * blockIdx.z + (size_t)bn * BN * ldb;

    int NT = K >> 6;
    if (KLIM) { int lim = (bm + 1) * (BM / 64); if (lim < NT) NT = lim; }

    f32x4 acc[MR][NR];
#pragma unroll
    for (int m = 0; m < MR; ++m)
#pragma unroll
        for (int n = 0; n < NR; ++n) acc[m][n] = (f32x4){0.f, 0.f, 0.f, 0.f};

// Stage one k-half of tile t: LDS dest linear (wave-uniform base + lane*16B),
// global source chunk pre-swizzled so the swizzled ds_read finds its bytes.
#define STAGE(t, kh)                                                              \
    {                                                                             \
        _Pragma("unroll")                                                         \
        for (int j = 0; j < Ak; ++j) {                                            \
            int row = (wid + j * 8) * 16 + lr;                                    \
            int c   = (kh) * 4 + (lsl ^ ((lr >> 1) & 3));                         \
            __builtin_amdgcn_global_load_lds(                                     \
                (const AS1 void*)(Ab + (size_t)(t) * 64 + (size_t)row * lda + c * 8), \
                (AS3 void*)(&lds[(t) & 1][(kh) * BM * 32] + (wid + j * 8) * 512), 16, 0, 0); \
        }                                                                         \
        _Pragma("unroll")                                                         \
        for (int j = 0; j < Bk; ++j) {                                            \
            int row = (wid + j * 8) * 16 + lr;                                    \
            int c   = (kh) * 4 + (lsl ^ ((lr >> 1) & 3));                         \
            __builtin_amdgcn_global_load_lds(                                     \
                (const AS1 void*)(Bb + (size_t)(t) * 64 + (size_t)row * ldb + c * 8), \
                (AS3 void*)(&lds[(t) & 1][BM * 64 + (kh) * BN * 32] + (wid + j * 8) * 512), 16, 0, 0); \
        }                                                                         \
    }

// Read all fragments of k-half kh and run the full MR x NR MFMA cluster.
#define PHASE_COMPUTE(t, kh)                                                      \
    {                                                                             \
        bf16x8 aq[MR], bq[NR];                                                    \
        _Pragma("unroll")                                                         \
        for (int m = 0; m < MR; ++m) {                                            \
            int row = wr * (BM / 2) + m * 16 + r15;                               \
            aq[m] = *(const bf16x8*)(&lds[(t) & 1][(kh) * BM * 32 + row * 32 + kswz]); \
        }                                                                         \
        _Pragma("unroll")                                                         \
        for (int n = 0; n < NR; ++n) {                                            \
            int col = wc * (BN / 4) + n * 16 + r15;                               \
            bq[n] = *(const bf16x8*)(&lds[(t) & 1][BM * 64 + (kh) * BN * 32 + col * 32 + kswz]); \
        }                                                                         \
        __builtin_amdgcn_s_setprio(1);                                            \
        _Pragma("unroll")                                                         \
        for (int m = 0; m < MR; ++m)                                              \
            _Pragma("unroll")                                                     \
            for (int n = 0; n < NR; ++n)                                          \
                acc[m][n] = __builtin_amdgcn_mfma_f32_16x16x32_bf16(aq[m], bq[n], acc[m][n], 0, 0, 0); \
        __builtin_amdgcn_s_setprio(0);                                            \
    }

    STAGE(0, 0); STAGE(0, 1);            // 2*(Ak+Bk) in flight

    for (int t = 0; t < NT - 1; ++t) {
        VMWAIT(Ak + Bk); SBAR(); SCHED();    // k0(t) landed; k1(t) still in flight
        STAGE(t + 1, 0);
        PHASE_COMPUTE(t, 0);
        SCHED();
        VMWAIT(Ak + Bk); SBAR(); SCHED();    // k1(t) landed; k0(t+1) in flight
        STAGE(t + 1, 1);
        PHASE_COMPUTE(t, 1);
        SCHED();
    }
    VMWAIT(Ak + Bk); SBAR(); SCHED();
    PHASE_COMPUTE(NT - 1, 0);
    SCHED();
    VMWAIT(0); SBAR(); SCHED();
    PHASE_COMPUTE(NT - 1, 1);

    // epilogue write: frag row = 4*(lane>>4)+r, col = lane&15
    size_t cz = strideC * blockIdx.z;
    const int rowb = bm * BM + wr * (BM / 2) + r4 * 4;
    const int colb = bn * BN + wc * (BN / 4) + r15;
#pragma unroll
    for (int m = 0; m < MR; ++m) {
#pragma unroll
        for (int r = 0; r < 4; ++r) {
            int row = rowb + m * 16 + r;
            size_t base = cz + (size_t)row * ldc + colb;
#pragma unroll
            for (int n = 0; n < NR; ++n) {
                float v = acc[m][n][r];
                size_t idx = base + n * 16;
                if (EPI == EPI_F32)       Cf[idx] = v;
                else if (EPI == EPI_BF16) Cb[idx] = f2bf(v);
                else if (EPI == EPI_RELU) Cb[idx] = f2bf(fmaxf(v, 0.f));
                else { float o = v + Res[idx]; Cf[idx] = o; Cb[idx] = f2bf(o); }
            }
        }
    }
#undef STAGE
#undef PHASE_COMPUTE
}

// ---------------------------------------------------------------------------
// Causal row softmax: scores fp32 [B][S][S] -> probs bf16 (zeros above diag)
// ---------------------------------------------------------------------------
__device__ __forceinline__ float wred_max(float v) {
#pragma unroll
    for (int off = 32; off; off >>= 1) v = fmaxf(v, __shfl_xor(v, off));
    return v;
}
__device__ __forceinline__ float wred_sum(float v) {
#pragma unroll
    for (int off = 32; off; off >>= 1) v += __shfl_xor(v, off);
    return v;
}

__global__ void bt_softmax(const float* __restrict__ scores, ushort* __restrict__ probs) {
    int row = blockIdx.x;
    int s   = row & (S_LEN - 1);
    const float* src = scores + (size_t)row * S_LEN;
    ushort*      dst = probs  + (size_t)row * S_LEN;
    int tid = threadIdx.x;
    int nvalid = s + 1;

    float vals[8];
    float mx = -1e30f;
#pragma unroll
    for (int j = 0; j < 8; ++j) {
        int t = tid + j * 256;
        float v = (t < nvalid) ? src[t] * 0.03125f : -1e30f;
        vals[j] = v;
        mx = fmaxf(mx, v);
    }
    __shared__ float red[4], red2[4];
    mx = wred_max(mx);
    if ((tid & 63) == 0) red[tid >> 6] = mx;
    __syncthreads();
    mx = fmaxf(fmaxf(red[0], red[1]), fmaxf(red[2], red[3]));

    float sum = 0.f, ps[8];
#pragma unroll
    for (int j = 0; j < 8; ++j) {
        float p = exp2f((vals[j] - mx) * 1.44269504f);
        ps[j] = p; sum += p;
    }
    sum = wred_sum(sum);
    if ((tid & 63) == 0) red2[tid >> 6] = sum;
    __syncthreads();
    sum = red2[0] + red2[1] + red2[2] + red2[3];
    float inv = 1.0f / sum;
#pragma unroll
    for (int j = 0; j < 8; ++j) {
        int t = tid + j * 256;
        dst[t] = (t < nvalid) ? f2bf(ps[j] * inv) : (ushort)0;
    }
}

// ---------------------------------------------------------------------------
// Last-token logits
// ---------------------------------------------------------------------------
__global__ void bt_logits(const float* __restrict__ h, const float* __restrict__ wout,
                          float* __restrict__ out) {
    __shared__ float hl[4][128];
    int tid = threadIdx.x;
    int d0 = blockIdx.y * 128;
    if (tid < 128) {
#pragma unroll
        for (int b = 0; b < 4; ++b)
            hl[b][tid] = h[((size_t)b * S_LEN + (S_LEN - 1)) * D_DIM + d0 + tid];
    }
    __syncthreads();
    int v = blockIdx.x * 256 + tid;
    float a0 = 0, a1 = 0, a2 = 0, a3 = 0;
    for (int j = 0; j < 128; ++j) {
        float w = wout[(size_t)(d0 + j) * V_DIM + v];
        a0 += hl[0][j] * w; a1 += hl[1][j] * w;
        a2 += hl[2][j] * w; a3 += hl[3][j] * w;
    }
    atomicAdd(out + v, a0);
    atomicAdd(out + V_DIM + v, a1);
    atomicAdd(out + 2 * V_DIM + v, a2);
    atomicAdd(out + 3 * V_DIM + v, a3);
}

// ---------------------------------------------------------------------------
extern "C" void kernel_launch(void* const* d_in, const int* in_sizes, int n_in,
                              void* d_out, int out_size, void* d_ws, size_t ws_size,
                              hipStream_t stream) {
    const int*   tokens = (const int*)d_in[0];
    const float* emb    = (const float*)d_in[1];
    const float* pe     = (const float*)d_in[2];
    const float* wgt[10];
    for (int i = 0; i < 10; ++i) wgt[i] = (const float*)d_in[3 + i];
    const float* wout = (const float*)d_in[13];

    char* w = (char*)d_ws;
    size_t o = 0;
    auto take = [&](size_t sz) { char* p = w + o; o += (sz + 255) & ~(size_t)255; return p; };

    const size_t DD = (size_t)D_DIM * D_DIM * 2;
    const size_t DH = (size_t)D_DIM * H_DIM * 2;
    size_t wsz[10] = {DD, DD, DD, DH, DH, DD, DD, DD, DH, DH};
    ushort* wT[10];
    for (int i = 0; i < 10; ++i) wT[i] = (ushort*)take(wsz[i]);

    const size_t NROW = (size_t)B_SZ * S_LEN;
    float*  h0     = (float*)take(NROW * D_DIM * 4);
    float*  h1     = (float*)take(NROW * D_DIM * 4);
    ushort* hbf    = (ushort*)take(NROW * D_DIM * 2);
    ushort* hresbf = (ushort*)take(NROW * D_DIM * 2);
    ushort* xkbf   = (ushort*)take(NROW * D_DIM * 2);
    ushort* xvt    = (ushort*)take((size_t)D_DIM * NROW * 2);
    ushort* hattn  = (ushort*)take(NROW * D_DIM * 2);
    char*   G      = take((size_t)B_SZ * S_LEN * S_LEN * 4 + (size_t)B_SZ * S_LEN * S_LEN * 2);
    float*  scores = (float*)G;
    ushort* probs  = (ushort*)(G + (size_t)B_SZ * S_LEN * S_LEN * 4);
    ushort* tbf    = (ushort*)G;   // FFN hidden aliases scores (disjoint phases)

    int wR[10] = {1024, 1024, 1024, 1024, 4096, 1024, 1024, 1024, 1024, 4096};
    int wC[10] = {1024, 1024, 1024, 4096, 1024, 1024, 1024, 1024, 4096, 1024};
    for (int i = 0; i < 10; ++i)
        bt_wtranspose<<<dim3(wC[i] / 64, wR[i] / 64), 256, 0, stream>>>(wgt[i], wT[i], wR[i], wC[i]);

    bt_embed<<<NROW, 256, 0, stream>>>(tokens, emb, pe, h0, hbf);

    auto layer = [&](ushort* wk, ushort* wv2, ushort* wo, ushort* w1, ushort* w2) {
        // xk = h @ wk : M=8192, N=1024, K=1024
        bt_gemm8<256, 128, EPI_BF16, false, false><<<dim3(8, 32, 1), 512, 0, stream>>>(
            hbf, wk, nullptr, xkbf, nullptr, D_DIM, D_DIM, D_DIM, D_DIM, 0, 0, 0);
        // xv^T = wv^T @ h^T : M=1024, N=8192, K=1024
        bt_gemm8<128, 256, EPI_BF16, false, false><<<dim3(32, 8, 1), 512, 0, stream>>>(
            wv2, hbf, nullptr, xvt, nullptr, D_DIM, D_DIM, (int)NROW, D_DIM, 0, 0, 0);
        // scores = Q @ K^T per batch (causal tiles only), fp32
        bt_gemm8<256, 128, EPI_F32, true, false><<<dim3(16, 8, B_SZ), 512, 0, stream>>>(
            hbf, xkbf, scores, nullptr, nullptr, D_DIM, D_DIM, S_LEN, D_DIM,
            (size_t)S_LEN * D_DIM, (size_t)S_LEN * D_DIM, (size_t)S_LEN * S_LEN);
        bt_softmax<<<NROW, 256, 0, stream>>>(scores, probs);
        // h_attn = probs @ xv (B^T = xv^T), causal K-limit
        bt_gemm8<256, 128, EPI_BF16, false, true><<<dim3(8, 8, B_SZ), 512, 0, stream>>>(
            probs, xvt, nullptr, hattn, nullptr, S_LEN, (int)NROW, D_DIM, S_LEN,
            (size_t)S_LEN * S_LEN, (size_t)S_LEN, (size_t)S_LEN * D_DIM);
        // h_res = h + h_attn @ wo
        bt_gemm8<256, 128, EPI_RES, false, false><<<dim3(8, 32, 1), 512, 0, stream>>>(
            hattn, wo, h1, hresbf, h0, D_DIM, D_DIM, D_DIM, D_DIM, 0, 0, 0);
        // t = relu(h_res @ w1) : M=8192, N=4096
        bt_gemm8<256, 256, EPI_RELU, false, false><<<dim3(16, 32, 1), 512, 0, stream>>>(
            hresbf, w1, nullptr, tbf, nullptr, D_DIM, D_DIM, H_DIM, D_DIM, 0, 0, 0);
        // h = h_res + t @ w2 : K=4096
        bt_gemm8<256, 128, EPI_RES, false, false><<<dim3(8, 32, 1), 512, 0, stream>>>(
            tbf, w2, h0, hbf, h1, H_DIM, H_DIM, D_DIM, H_DIM, 0, 0, 0);
    };
    layer(wT[0], wT[1], wT[2], wT[3], wT[4]);
    layer(wT[5], wT[6], wT[7], wT[8], wT[9]);

    hipMemsetAsync(d_out, 0, (size_t)B_SZ * V_DIM * sizeof(float), stream);
    bt_logits<<<dim3(V_DIM / 256, D_DIM / 128), 256, 0, stream>>>(h0, wout, (float*)d_out);
}

// Round 4
// 830.817 us; speedup vs baseline: 1.0999x; 1.0999x over previous
//
#include <hip/hip_runtime.h>

#define S_LEN 2048
#define D_DIM 1024
#define H_DIM 4096
#define V_DIM 32000
#define B_SZ  4

typedef float  f32x4  __attribute__((ext_vector_type(4)));
typedef __bf16 bf16x8 __attribute__((ext_vector_type(8)));

__device__ __forceinline__ ushort f2bf(float f) {
    union { float f; unsigned u; } v; v.f = f;
    unsigned r = v.u + 0x7fffu + ((v.u >> 16) & 1u);
    return (ushort)(r >> 16);
}

// ---------------------------------------------------------------------------
// Weight transpose + fp32->bf16 convert: in fp32 [R][C] -> out bf16 [C][R]
// ---------------------------------------------------------------------------
__global__ void bt_wtranspose(const float* __restrict__ in, ushort* __restrict__ out,
                              int R, int C) {
    __shared__ ushort s[64][65];
    int r0 = blockIdx.y * 64, c0 = blockIdx.x * 64;
    int t = threadIdx.x;
    int lr = t >> 2, lc4 = (t & 3) * 16;
    const float* src = in + (size_t)(r0 + lr) * C + c0 + lc4;
#pragma unroll
    for (int j = 0; j < 4; ++j) {
        float4 v = ((const float4*)src)[j];
        s[lr][lc4 + 4 * j + 0] = f2bf(v.x);
        s[lr][lc4 + 4 * j + 1] = f2bf(v.y);
        s[lr][lc4 + 4 * j + 2] = f2bf(v.z);
        s[lr][lc4 + 4 * j + 3] = f2bf(v.w);
    }
    __syncthreads();
    int oc = t >> 2, orr = (t & 3) * 16;
    ushort tmp[16] __attribute__((aligned(16)));
#pragma unroll
    for (int j = 0; j < 16; ++j) tmp[j] = s[orr + j][oc];
    ushort* dst = out + (size_t)(c0 + oc) * R + r0 + orr;
    *(uint4*)dst        = *(uint4*)tmp;
    *(uint4*)(dst + 8)  = *(uint4*)(tmp + 8);
}

// ---------------------------------------------------------------------------
// Embedding + positional encoding
// ---------------------------------------------------------------------------
__global__ void bt_embed(const int* __restrict__ tokens, const float* __restrict__ emb,
                         const float* __restrict__ pe, float* __restrict__ h,
                         ushort* __restrict__ hbf) {
    int row = blockIdx.x;
    int s   = row & (S_LEN - 1);
    int tok = tokens[row];
    int t   = threadIdx.x;
    float4 v = ((const float4*)(emb + (size_t)tok * D_DIM))[t];
    float4 p = ((const float4*)(pe + (size_t)s * D_DIM))[t];
    v.x += p.x; v.y += p.y; v.z += p.z; v.w += p.w;
    ((float4*)(h + (size_t)row * D_DIM))[t] = v;
    uint2 pk;
    pk.x = (unsigned)f2bf(v.x) | ((unsigned)f2bf(v.y) << 16);
    pk.y = (unsigned)f2bf(v.z) | ((unsigned)f2bf(v.w) << 16);
    ((uint2*)(hbf + (size_t)row * D_DIM))[t] = pk;
}

// ---------------------------------------------------------------------------
// Ring-4 K-split pipelined B^T GEMM: C[m][n] = sum_k A[m][k]*B[n][k]
// BK=64 in two K=32 half-steps; 4 single-half LDS buffers; prefetch depth 3
// half-steps (covers ~900cy HBM latency); counted vmcnt (never 0 in main
// loop); raw s_barrier; setprio around MFMA cluster; XCD band swizzle.
// ---------------------------------------------------------------------------
#define EPI_F32  0
#define EPI_BF16 1
#define EPI_RELU 2
#define EPI_RES  3

#define VMWAIT(N) asm volatile("s_waitcnt vmcnt(%0)" :: "n"(N) : "memory")
#define SBAR()  __builtin_amdgcn_s_barrier()
#define SCHED() __builtin_amdgcn_sched_barrier(0)
#define AS1 __attribute__((address_space(1)))
#define AS3 __attribute__((address_space(3)))

// SWZ: 0 = identity; 1 = XCD owns a band of bm rows (big-A kernels);
//      2 = XCD owns a band of bn cols (big-B kernels). Requires gy%8==0 (1)
//      or gx%8==0 (2).
template <int BM, int BN, int EPI, bool CSKIP, bool KLIM, int SWZ>
__global__ __launch_bounds__(512, 1)
void bt_gemm8(const ushort* __restrict__ A, const ushort* __restrict__ B,
              float* Cf, ushort* Cb, const float* __restrict__ Res,
              int lda, int ldb, int ldc, int K,
              size_t strideA, size_t strideB, size_t strideC) {
    constexpr int MR = BM / 32;      // A frags per wave (wave owns BM/2 rows)
    constexpr int NR = BN / 64;      // B frags per wave (wave owns BN/4 cols)
    constexpr int Ak = BM / 128;     // stage instrs per wave per A k-half
    constexpr int Bk = BN / 128;
    constexpr int G  = Ak + Bk;      // loads in flight per stage group
    constexpr int HS = (BM + BN) * 32;   // ushorts per k-half buffer

    __shared__ ushort lds[4][HS];

    int bm, bn;
    if (SWZ == 1) {
        int gx = gridDim.x, gy = gridDim.y;
        int id = blockIdx.y * gx + blockIdx.x;
        int xcd = id & 7, slot = id >> 3;
        int bandH = gy >> 3;
        bm = xcd * bandH + (slot % bandH);
        bn = slot / bandH;
    } else if (SWZ == 2) {
        int gx = gridDim.x;
        int id = blockIdx.y * gx + blockIdx.x;
        int xcd = id & 7, slot = id >> 3;
        int bandW = gx >> 3;
        bn = xcd * bandW + (slot % bandW);
        bm = slot / bandW;
    } else { bm = blockIdx.y; bn = blockIdx.x; }

    if (CSKIP && bn * BN >= (bm + 1) * BM) return;

    const int tid  = threadIdx.x;
    const int lane = tid & 63;
    const int wid  = tid >> 6;
    const int wr   = wid >> 2, wc = wid & 3;
    const int r15  = lane & 15, r4 = lane >> 4;
    const int lr   = lane >> 2;          // stage: row-within-16
    const int lsl  = lane & 3;           // stage: 16B slot
    const int kswz = (r4 ^ ((r15 >> 1) & 3)) * 8;  // read-side slot XOR

    const ushort* Ab = A + strideA * blockIdx.z + (size_t)bm * BM * lda;
    const ushort* Bb = B + strideB * blockIdx.z + (size_t)bn * BN * ldb;

    int NT = K >> 6;
    if (KLIM) { int lim = (bm + 1) * (BM / 64); if (lim < NT) NT = lim; }

    f32x4 acc[MR][NR];
#pragma unroll
    for (int m = 0; m < MR; ++m)
#pragma unroll
        for (int n = 0; n < NR; ++n) acc[m][n] = (f32x4){0.f, 0.f, 0.f, 0.f};

// Stage half-step hs (tile hs>>1, k-half hs&1) into ring buffer hs&3.
// LDS dest linear (wave-uniform base + lane*16B); global source chunk
// pre-swizzled so the swizzled ds_read finds its bytes.
#define STAGE(hs)                                                                 \
    {                                                                             \
        const int t_ = (hs) >> 1, b_ = (hs) & 3;                                  \
        const int c_ = ((hs) & 1) * 4 + (lsl ^ ((lr >> 1) & 3));                  \
        _Pragma("unroll")                                                         \
        for (int j = 0; j < Ak; ++j) {                                            \
            int row = (wid + j * 8) * 16 + lr;                                    \
            __builtin_amdgcn_global_load_lds(                                     \
                (const AS1 void*)(Ab + (size_t)t_ * 64 + (size_t)row * lda + c_ * 8), \
                (AS3 void*)(&lds[b_][0] + (wid + j * 8) * 512), 16, 0, 0);        \
        }                                                                         \
        _Pragma("unroll")                                                         \
        for (int j = 0; j < Bk; ++j) {                                            \
            int row = (wid + j * 8) * 16 + lr;                                    \
            __builtin_amdgcn_global_lo\
ad_lds(                                                                           \
                (const AS1 void*)(Bb + (size_t)t_ * 64 + (size_t)row * ldb + c_ * 8), \
                (AS3 void*)(&lds[b_][BM * 32] + (wid + j * 8) * 512), 16, 0, 0);  \
        }                                                                         \
    }

#define PHASE_COMPUTE(hs)                                                         \
    {                                                                             \
        const int b_ = (hs) & 3;                                                  \
        bf16x8 aq[MR], bq[NR];                                                    \
        _Pragma("unroll")                                                         \
        for (int m = 0; m < MR; ++m) {                                            \
            int row = wr * (BM / 2) + m * 16 + r15;                               \
            aq[m] = *(const bf16x8*)(&lds[b_][row * 32 + kswz]);                  \
        }                                                                         \
        _Pragma("unroll")                                                         \
        for (int n = 0; n < NR; ++n) {                                            \
            int col = wc * (BN / 4) + n * 16 + r15;                               \
            bq[n] = *(const bf16x8*)(&lds[b_][BM * 32 + col * 32 + kswz]);        \
        }                                                                         \
        __builtin_amdgcn_s_setprio(1);                                            \
        _Pragma("unroll")                                                         \
        for (int m = 0; m < MR; ++m)                                              \
            _Pragma("unroll")                                                     \
            for (int n = 0; n < NR; ++n)                                          \
                acc[m][n] = __builtin_amdgcn_mfma_f32_16x16x32_bf16(aq[m], bq[n], acc[m][n], 0, 0, 0); \
        __builtin_amdgcn_s_setprio(0);                                            \
    }

    STAGE(0); STAGE(1); STAGE(2);        // 3 groups (3G loads) in flight

    const int NH2 = 2 * NT;
    for (int hs = 0; hs < NH2 - 3; ++hs) {
        VMWAIT(2 * G); SBAR(); SCHED();  // group hs landed; hs+1, hs+2 in flight
        STAGE(hs + 3);                   // refill: writes buffer (hs-1)&3 (already consumed)
        PHASE_COMPUTE(hs);
        SCHED();
    }
    VMWAIT(2 * G); SBAR(); SCHED();
    PHASE_COMPUTE(NH2 - 3);
    SCHED();
    VMWAIT(G); SBAR(); SCHED();
    PHASE_COMPUTE(NH2 - 2);
    SCHED();
    VMWAIT(0); SBAR(); SCHED();
    PHASE_COMPUTE(NH2 - 1);

    // epilogue write: frag row = 4*(lane>>4)+r, col = lane&15
    size_t cz = strideC * blockIdx.z;
    const int rowb = bm * BM + wr * (BM / 2) + r4 * 4;
    const int colb = bn * BN + wc * (BN / 4) + r15;
#pragma unroll
    for (int m = 0; m < MR; ++m) {
#pragma unroll
        for (int r = 0; r < 4; ++r) {
            int row = rowb + m * 16 + r;
            size_t base = cz + (size_t)row * ldc + colb;
#pragma unroll
            for (int n = 0; n < NR; ++n) {
                float v = acc[m][n][r];
                size_t idx = base + n * 16;
                if (EPI == EPI_F32)       Cf[idx] = v;
                else if (EPI == EPI_BF16) Cb[idx] = f2bf(v);
                else if (EPI == EPI_RELU) Cb[idx] = f2bf(fmaxf(v, 0.f));
                else { float o = v + Res[idx]; Cf[idx] = o; Cb[idx] = f2bf(o); }
            }
        }
    }
#undef STAGE
#undef PHASE_COMPUTE
}

// ---------------------------------------------------------------------------
// Causal row softmax: scores fp32 [B][S][S] -> probs bf16 (zeros above diag)
// ---------------------------------------------------------------------------
__device__ __forceinline__ float wred_max(float v) {
#pragma unroll
    for (int off = 32; off; off >>= 1) v = fmaxf(v, __shfl_xor(v, off));
    return v;
}
__device__ __forceinline__ float wred_sum(float v) {
#pragma unroll
    for (int off = 32; off; off >>= 1) v += __shfl_xor(v, off);
    return v;
}

__global__ void bt_softmax(const float* __restrict__ scores, ushort* __restrict__ probs) {
    int row = blockIdx.x;
    int s   = row & (S_LEN - 1);
    const float* src = scores + (size_t)row * S_LEN;
    ushort*      dst = probs  + (size_t)row * S_LEN;
    int tid = threadIdx.x;
    int nvalid = s + 1;

    float vals[8];
    float mx = -1e30f;
#pragma unroll
    for (int j = 0; j < 8; ++j) {
        int t = tid + j * 256;
        float v = (t < nvalid) ? src[t] * 0.03125f : -1e30f;
        vals[j] = v;
        mx = fmaxf(mx, v);
    }
    __shared__ float red[4], red2[4];
    mx = wred_max(mx);
    if ((tid & 63) == 0) red[tid >> 6] = mx;
    __syncthreads();
    mx = fmaxf(fmaxf(red[0], red[1]), fmaxf(red[2], red[3]));

    float sum = 0.f, ps[8];
#pragma unroll
    for (int j = 0; j < 8; ++j) {
        float p = exp2f((vals[j] - mx) * 1.44269504f);
        ps[j] = p; sum += p;
    }
    sum = wred_sum(sum);
    if ((tid & 63) == 0) red2[tid >> 6] = sum;
    __syncthreads();
    sum = red2[0] + red2[1] + red2[2] + red2[3];
    float inv = 1.0f / sum;
#pragma unroll
    for (int j = 0; j < 8; ++j) {
        int t = tid + j * 256;
        dst[t] = (t < nvalid) ? f2bf(ps[j] * inv) : (ushort)0;
    }
}

// ---------------------------------------------------------------------------
// Last-token logits
// ---------------------------------------------------------------------------
__global__ void bt_logits(const float* __restrict__ h, const float* __restrict__ wout,
                          float* __restrict__ out) {
    __shared__ float hl[4][128];
    int tid = threadIdx.x;
    int d0 = blockIdx.y * 128;
    if (tid < 128) {
#pragma unroll
        for (int b = 0; b < 4; ++b)
            hl[b][tid] = h[((size_t)b * S_LEN + (S_LEN - 1)) * D_DIM + d0 + tid];
    }
    __syncthreads();
    int v = blockIdx.x * 256 + tid;
    float a0 = 0, a1 = 0, a2 = 0, a3 = 0;
    for (int j = 0; j < 128; ++j) {
        float w = wout[(size_t)(d0 + j) * V_DIM + v];
        a0 += hl[0][j] * w; a1 += hl[1][j] * w;
        a2 += hl[2][j] * w; a3 += hl[3][j] * w;
    }
    atomicAdd(out + v, a0);
    atomicAdd(out + V_DIM + v, a1);
    atomicAdd(out + 2 * V_DIM + v, a2);
    atomicAdd(out + 3 * V_DIM + v, a3);
}

// ---------------------------------------------------------------------------
extern "C" void kernel_launch(void* const* d_in, const int* in_sizes, int n_in,
                              void* d_out, int out_size, void* d_ws, size_t ws_size,
                              hipStream_t stream) {
    const int*   tokens = (const int*)d_in[0];
    const float* emb    = (const float*)d_in[1];
    const float* pe     = (const float*)d_in[2];
    const float* wgt[10];
    for (int i = 0; i < 10; ++i) wgt[i] = (const float*)d_in[3 + i];
    const float* wout = (const float*)d_in[13];

    char* w = (char*)d_ws;
    size_t o = 0;
    auto take = [&](size_t sz) { char* p = w + o; o += (sz + 255) & ~(size_t)255; return p; };

    const size_t DD = (size_t)D_DIM * D_DIM * 2;
    const size_t DH = (size_t)D_DIM * H_DIM * 2;
    size_t wsz[10] = {DD, DD, DD, DH, DH, DD, DD, DD, DH, DH};
    ushort* wT[10];
    for (int i = 0; i < 10; ++i) wT[i] = (ushort*)take(wsz[i]);

    const size_t NROW = (size_t)B_SZ * S_LEN;
    float*  h0     = (float*)take(NROW * D_DIM * 4);
    float*  h1     = (float*)take(NROW * D_DIM * 4);
    ushort* hbf    = (ushort*)take(NROW * D_DIM * 2);
    ushort* hresbf = (ushort*)take(NROW * D_DIM * 2);
    ushort* xkbf   = (ushort*)take(NROW * D_DIM * 2);
    ushort* xvt    = (ushort*)take((size_t)D_DIM * NROW * 2);
    ushort* hattn  = (ushort*)take(NROW * D_DIM * 2);
    char*   G      = take((size_t)B_SZ * S_LEN * S_LEN * 4 + (size_t)B_SZ * S_LEN * S_LEN * 2);
    float*  scores = (float*)G;
    ushort* probs  = (ushort*)(G + (size_t)B_SZ * S_LEN * S_LEN * 4);
    ushort* tbf    = (ushort*)G;   // FFN hidden aliases scores (disjoint phases)

    int wR[10] = {1024, 1024, 1024, 1024, 4096, 1024, 1024, 1024, 1024, 4096};
    int wC[10] = {1024, 1024, 1024, 4096, 1024, 1024, 1024, 1024, 4096, 1024};
    for (int i = 0; i < 10; ++i)
        bt_wtranspose<<<dim3(wC[i] / 64, wR[i] / 64), 256, 0, stream>>>(wgt[i], wT[i], wR[i], wC[i]);

    bt_embed<<<NROW, 256, 0, stream>>>(tokens, emb, pe, h0, hbf);

    auto layer = [&](ushort* wk, ushort* wv2, ushort* wo, ushort* w1, ushort* w2) {
        // xk = h @ wk : M=8192, N=1024, K=1024  (A big -> bm bands)
        bt_gemm8<256, 128, EPI_BF16, false, false, 1><<<dim3(8, 32, 1), 512, 0, stream>>>(
            hbf, wk, nullptr, xkbf, nullptr, D_DIM, D_DIM, D_DIM, D_DIM, 0, 0, 0);
        // xv^T = wv^T @ h^T : M=1024, N=8192, K=1024  (B big -> bn bands)
        bt_gemm8<128, 256, EPI_BF16, false, false, 2><<<dim3(32, 8, 1), 512, 0, stream>>>(
            wv2, hbf, nullptr, xvt, nullptr, D_DIM, D_DIM, (int)NROW, D_DIM, 0, 0, 0);
        // scores = Q @ K^T per batch (causal tiles only), fp32
        bt_gemm8<256, 128, EPI_F32, true, false, 0><<<dim3(16, 8, B_SZ), 512, 0, stream>>>(
            hbf, xkbf, scores, nullptr, nullptr, D_DIM, D_DIM, S_LEN, D_DIM,
            (size_t)S_LEN * D_DIM, (size_t)S_LEN * D_DIM, (size_t)S_LEN * S_LEN);
        bt_softmax<<<NROW, 256, 0, stream>>>(scores, probs);
        // h_attn = probs @ xv (B^T = xv^T), causal K-limit
        bt_gemm8<256, 128, EPI_BF16, false, true, 0><<<dim3(8, 8, B_SZ), 512, 0, stream>>>(
            probs, xvt, nullptr, hattn, nullptr, S_LEN, (int)NROW, D_DIM, S_LEN,
            (size_t)S_LEN * S_LEN, (size_t)S_LEN, (size_t)S_LEN * D_DIM);
        // h_res = h + h_attn @ wo
        bt_gemm8<256, 128, EPI_RES, false, false, 1><<<dim3(8, 32, 1), 512, 0, stream>>>(
            hattn, wo, h1, hresbf, h0, D_DIM, D_DIM, D_DIM, D_DIM, 0, 0, 0);
        // t = relu(h_res @ w1) : M=8192, N=4096
        bt_gemm8<256, 256, EPI_RELU, false, false, 1><<<dim3(16, 32, 1), 512, 0, stream>>>(
            hresbf, w1, nullptr, tbf, nullptr, D_DIM, D_DIM, H_DIM, D_DIM, 0, 0, 0);
        // h = h_res + t @ w2 : K=4096
        bt_gemm8<256, 128, EPI_RES, false, false, 1><<<dim3(8, 32, 1), 512, 0, stream>>>(
            tbf, w2, h0, hbf, h1, H_DIM, H_DIM, D_DIM, H_DIM, 0, 0, 0);
    };
    layer(wT[0], wT[1], wT[2], wT[3], wT[4]);
    layer(wT[5], wT[6], wT[7], wT[8], wT[9]);

    hipMemsetAsync(d_out, 0, (size_t)B_SZ * V_DIM * sizeof(float), stream);
    bt_logits<<<dim3(V_DIM / 256, D_DIM / 128), 256, 0, stream>>>(h0, wout, (float*)d_out);
}